// Round 2
// baseline (11866.055 us; speedup 1.0000x reference)
//
#include <hip/hip_runtime.h>
#include <stdint.h>
#include <math.h>

typedef unsigned int uint;
typedef unsigned long long ull;

#define BATCH 2
#define ATOTAL 242991
#define KSEL 4741
#define NW 75
#define POST_NMS 1000

// level constants (host + compile-time device use)
constexpr int cH[5]       = {200,100,50,25,13};
constexpr int cW[5]       = {304,152,76,38,19};
constexpr int cStrideL[5] = {4,8,16,32,64};
constexpr int cSizeL[5]   = {32,64,128,256,512};
constexpr int cLoff[5]    = {0,182400,228000,239400,242250};
constexpr int cCount[5]   = {182400,45600,11400,2850,741};
constexpr int cSeg[5]     = {0,1000,2000,3000,4000};
constexpr int cSegK[5]    = {1000,1000,1000,1000,741};

// runtime-indexed device copies
__device__ __constant__ int dLoff[5]  = {0,182400,228000,239400,242250};
__device__ __constant__ int dCount[5] = {182400,45600,11400,2850,741};
__device__ __constant__ int dSeg[5]   = {0,1000,2000,3000,4000};
__device__ __constant__ int dSegK[5]  = {1000,1000,1000,1000,741};

__device__ __forceinline__ uint fkey(float f) {
    uint u = __float_as_uint(f);
    return (u & 0x80000000u) ? ~u : (u | 0x80000000u);
}

// ---------------- weight transpose: conv_w [O=256][K=2304] -> wT [K][O] ----------------
__global__ __launch_bounds__(256) void wt_kernel(const float* __restrict__ conv_w,
                                                 float* __restrict__ wT) {
    int t = blockIdx.x * 256 + threadIdx.x;
    if (t < 2304 * 256) {
        int oc = t & 255, k = t >> 8;
        wT[t] = conv_w[oc * 2304 + k];
    }
}

// ---------------- fused conv3x3+relu + 1x1 heads (f64) + decode (f64) + clip ----------------
// block: 256 threads. tile: 4 rows x 16 cols = 64 px. all 256 t-channels in 4 groups of 64.
template <int LVL>
__global__ __launch_bounds__(256) void conv_fused(
    const float* __restrict__ feat, const float* __restrict__ wT,
    const float* __restrict__ conv_b,
    const float* __restrict__ cls_w, const float* __restrict__ cls_b,
    const float* __restrict__ box_w, const float* __restrict__ box_b,
    float* __restrict__ scoresA, float* __restrict__ boxesA)
{
    constexpr int H = cH[LVL], W = cW[LVL];
    constexpr int STRIDE = cStrideL[LVL], SZ = cSizeL[LVL], LOFF = cLoff[LVL];
    constexpr int TILESX = (W + 15) / 16;

    const int tile = blockIdx.x;
    const int b    = blockIdx.y;
    const int ty0  = (tile / TILESX) * 4;
    const int tx0  = (tile % TILESX) * 16;
    const int tid  = threadIdx.x;

    __shared__ float hwS[256 * 16];                 // [oc][16 heads] 16 KiB
    __shared__ __align__(16) char uni[22336];       // union region
    float*  inS   = (float*)uni;                    // [8][6][20]  (3840 B)
    float*  wS    = (float*)(uni + 3840);           // [72][64]    (18432 B)
    float*  tS    = (float*)uni;                    // [64][68]    (17408 B)
    double* houtD = (double*)uni;                   // [64][16]    (8192 B)

    // stage head weights once
    for (int e = tid; e < 256 * 16; e += 256) {
        int oc = e >> 4, h = e & 15;
        float v = 0.f;
        if (h < 3)        v = cls_w[h * 256 + oc];
        else if (h < 15)  v = box_w[(h - 3) * 256 + oc];
        hwS[e] = v;
    }

    const int p = tid & 15, o = tid >> 4;    // p: pixel group, o: oc group (4 oc each)
    const int r = p >> 2, cg4 = (p & 3) * 4; // row in tile, col base

    double hacc[4] = {0.0, 0.0, 0.0, 0.0};   // f64 head accumulators
    const float* fb = feat + (size_t)b * 256 * H * W;

    for (int ocg = 0; ocg < 4; ++ocg) {
        float acc[4][4];
#pragma unroll
        for (int px = 0; px < 4; ++px)
#pragma unroll
            for (int j = 0; j < 4; ++j) acc[px][j] = 0.f;

        for (int icb = 0; icb < 32; ++icb) {
            __syncthreads();
            // stage input patch 8ic x 6rows x 18cols (row stride 20)
            for (int e = tid; e < 8 * 6 * 18; e += 256) {
                int ic = e / 108; int rem = e - ic * 108;
                int row = rem / 18; int col = rem - row * 18;
                int gy = ty0 + row - 1, gx = tx0 + col - 1;
                float v = 0.f;
                if (gy >= 0 && gy < H && gx >= 0 && gx < W)
                    v = fb[((icb * 8 + ic) * H + gy) * W + gx];
                inS[(ic * 6 + row) * 20 + col] = v;
            }
            // stage weights 72k x 64oc
            for (int e = tid; e < 72 * 64; e += 256) {
                int kk = e >> 6, oc = e & 63;
                wS[kk * 64 + oc] = wT[(size_t)(icb * 72 + kk) * 256 + (ocg << 6) + oc];
            }
            __syncthreads();
#pragma unroll
            for (int ic = 0; ic < 8; ++ic) {
#pragma unroll
                for (int dy = 0; dy < 3; ++dy) {
                    const float* ip = &inS[(ic * 6 + r + dy) * 20 + cg4];
                    float4 va = *(const float4*)ip;
                    float2 vb = *(const float2*)(ip + 4);
                    float in6[6] = {va.x, va.y, va.z, va.w, vb.x, vb.y};
#pragma unroll
                    for (int dx = 0; dx < 3; ++dx) {
                        float4 w4 = *(const float4*)&wS[(ic * 9 + dy * 3 + dx) * 64 + (o << 2)];
#pragma unroll
                        for (int px = 0; px < 4; ++px) {
                            float iv = in6[px + dx];
                            acc[px][0] = fmaf(iv, w4.x, acc[px][0]);
                            acc[px][1] = fmaf(iv, w4.y, acc[px][1]);
                            acc[px][2] = fmaf(iv, w4.z, acc[px][2]);
                            acc[px][3] = fmaf(iv, w4.w, acc[px][3]);
                        }
                    }
                }
            }
        }
        __syncthreads();   // all inS/wS reads done before tS overwrite (aliased)
        {
            float4 cb = *(const float4*)&conv_b[(ocg << 6) + (o << 2)];
#pragma unroll
            for (int px = 0; px < 4; ++px) {
                int pxi = r * 16 + cg4 + px;
                float4 tv;
                tv.x = fmaxf(acc[px][0] + cb.x, 0.f);
                tv.y = fmaxf(acc[px][1] + cb.y, 0.f);
                tv.z = fmaxf(acc[px][2] + cb.z, 0.f);
                tv.w = fmaxf(acc[px][3] + cb.w, 0.f);
                *(float4*)&tS[pxi * 68 + (o << 2)] = tv;
            }
        }
        __syncthreads();
        // head accumulate in f64: thread (px2, s) does heads s*4..s*4+3 for pixel px2
        {
            const int px2 = tid & 63;
            const int s4  = (tid >> 6) << 2;
#pragma unroll
            for (int oc4 = 0; oc4 < 16; ++oc4) {
                float4 tv = *(const float4*)&tS[px2 * 68 + (oc4 << 2)];
                const float* hb = &hwS[(((ocg << 6) + (oc4 << 2))) * 16 + s4];
                float4 h0 = *(const float4*)(hb);
                float4 h1 = *(const float4*)(hb + 16);
                float4 h2 = *(const float4*)(hb + 32);
                float4 h3 = *(const float4*)(hb + 48);
                hacc[0] += (double)tv.x*(double)h0.x + (double)tv.y*(double)h1.x
                         + (double)tv.z*(double)h2.x + (double)tv.w*(double)h3.x;
                hacc[1] += (double)tv.x*(double)h0.y + (double)tv.y*(double)h1.y
                         + (double)tv.z*(double)h2.y + (double)tv.w*(double)h3.y;
                hacc[2] += (double)tv.x*(double)h0.z + (double)tv.y*(double)h1.z
                         + (double)tv.z*(double)h2.z + (double)tv.w*(double)h3.z;
                hacc[3] += (double)tv.x*(double)h0.w + (double)tv.y*(double)h1.w
                         + (double)tv.z*(double)h2.w + (double)tv.w*(double)h3.w;
            }
        }
    }
    __syncthreads();
    {
        const int px2 = tid & 63;
        const int s4  = (tid >> 6) << 2;
        houtD[px2 * 16 + s4 + 0] = hacc[0];
        houtD[px2 * 16 + s4 + 1] = hacc[1];
        houtD[px2 * 16 + s4 + 2] = hacc[2];
        houtD[px2 * 16 + s4 + 3] = hacc[3];
    }
    __syncthreads();
    // decode + clip in f64 + store f32. thread (px2, a)
    {
        const int px2 = tid & 63;
        const int a   = tid >> 6;
        const int gy = ty0 + (px2 >> 4);
        const int gx = tx0 + (px2 & 15);
        if (a < 3 && gy < H && gx < W) {
            double score = houtD[px2 * 16 + a] + (double)cls_b[a];
            double rg0 = houtD[px2 * 16 + 3 + a * 4 + 0] + (double)box_b[a * 4 + 0];
            double rg1 = houtD[px2 * 16 + 3 + a * 4 + 1] + (double)box_b[a * 4 + 1];
            double rg2 = houtD[px2 * 16 + 3 + a * 4 + 2] + (double)box_b[a * 4 + 2];
            double rg3 = houtD[px2 * 16 + 3 + a * 4 + 3] + (double)box_b[a * 4 + 3];
            // anchor (replicates numpy float64 construction -> f32 cast)
            double ratio = (a == 0) ? 0.5 : ((a == 1) ? 1.0 : 2.0);
            double hr = sqrt(ratio), wr = 1.0 / hr;
            double wsd = wr * (double)SZ, hsd = hr * (double)SZ;
            double sx = (double)(gx * STRIDE), sy = (double)(gy * STRIDE);
            float ax0 = (float)(sx - 0.5 * wsd);
            float ay0 = (float)(sy - 0.5 * hsd);
            float ax1 = (float)(sx + 0.5 * wsd);
            float ay1 = (float)(sy + 0.5 * hsd);
            // decode in f64 on the f32-rounded anchors (JAX semantics, np-f64 accuracy)
            double wa = (double)ax1 - (double)ax0, ha = (double)ay1 - (double)ay0;
            double cxa = (double)ax0 + 0.5 * wa, cya = (double)ay0 + 0.5 * ha;
            double dwv = fmin(rg2, 4.135166556742356);
            double dhv = fmin(rg3, 4.135166556742356);
            double cx = rg0 * wa + cxa, cy = rg1 * ha + cya;
            double w = exp(dwv) * wa, h = exp(dhv) * ha;
            double x0 = cx - 0.5 * w, y0 = cy - 0.5 * h;
            double x1 = cx + 0.5 * w, y1 = cy + 0.5 * h;
            x0 = fmin(fmax(x0, 0.0), 1216.0);
            y0 = fmin(fmax(y0, 0.0), 800.0);
            x1 = fmin(fmax(x1, 0.0), 1216.0);
            y1 = fmin(fmax(y1, 0.0), 800.0);
            int gidx = LOFF + (gy * W + gx) * 3 + a;
            scoresA[(size_t)b * ATOTAL + gidx] = (float)score;
            float4 bx = make_float4((float)x0, (float)y0, (float)x1, (float)y1);
            *(float4*)&boxesA[((size_t)b * ATOTAL + gidx) * 4] = bx;
        }
    }
}

// ---------------- per-(batch,level) top-k via 3-pass radix threshold ----------------
__global__ __launch_bounds__(256) void topk_kernel(
    const float* __restrict__ scoresA, const float* __restrict__ boxesA,
    float* __restrict__ selScore, float* __restrict__ selBox,
    int* __restrict__ selValid, int* __restrict__ selAnchor)
{
    const int lvl = blockIdx.x, b = blockIdx.y;
    const int n = dCount[lvl], loff = dLoff[lvl], seg = dSeg[lvl], k = dSegK[lvl];
    const float* sc = scoresA + (size_t)b * ATOTAL + loff;
    const int tid = threadIdx.x;

    float* oS = selScore + b * KSEL;
    float* oB = selBox + (size_t)b * KSEL * 4;
    int* oV = selValid + b * KSEL;
    int* oA = selAnchor + b * KSEL;

    auto emit = [&](int slot, int i) {
        int g = loff + i;
        float s = sc[i];
        float4 bx = *(const float4*)&boxesA[((size_t)b * ATOTAL + g) * 4];
        oS[seg + slot] = s;
        *(float4*)&oB[(size_t)(seg + slot) * 4] = bx;
        oV[seg + slot] = ((bx.z - bx.x) >= 1e-3f && (bx.w - bx.y) >= 1e-3f) ? 1 : 0;
        oA[seg + slot] = g;
    };

    if (n <= k) {
        for (int i = tid; i < n; i += 256) emit(i, i);
        return;
    }

    __shared__ uint hist[2048];
    __shared__ uint sh_bin, sh_krem;
    __shared__ uint cntG, cntE;
    __shared__ int stash[64];

    uint krem = (uint)k;
    uint prefix = 0;
    for (int pass = 0; pass < 3; ++pass) {
        for (int e = tid; e < 2048; e += 256) hist[e] = 0;
        __syncthreads();
        for (int i = tid; i < n; i += 256) {
            uint key = fkey(sc[i]);
            uint bin; bool sel;
            if (pass == 0)      { sel = true;                      bin = key >> 21; }
            else if (pass == 1) { sel = ((key >> 21) == prefix);   bin = (key >> 10) & 0x7FFu; }
            else                { sel = ((key >> 10) == prefix);   bin = key & 0x3FFu; }
            if (sel) atomicAdd(&hist[bin], 1u);
        }
        __syncthreads();
        if (tid == 0) {
            int nb = (pass == 2) ? 1024 : 2048;
            uint c = 0;
            for (int x = nb - 1; x >= 0; --x) {
                uint h = hist[x];
                if (c + h >= krem) { sh_bin = (uint)x; sh_krem = krem - c; break; }
                c += h;
            }
        }
        __syncthreads();
        uint bin = sh_bin; krem = sh_krem;
        if (pass == 0)      prefix = bin;
        else if (pass == 1) prefix = (prefix << 11) | bin;
        else                prefix = (prefix << 10) | bin;
        __syncthreads();
    }
    const uint T = prefix;
    const uint need_eq = krem;
    if (tid == 0) { cntG = 0; cntE = 0; }
    __syncthreads();
    for (int i = tid; i < n; i += 256) {
        uint key = fkey(sc[i]);
        if (key > T) {
            uint pos = atomicAdd(&cntG, 1u);
            emit((int)pos, i);
        } else if (key == T) {
            uint e = atomicAdd(&cntE, 1u);
            if (e < 64) stash[e] = i;
        }
    }
    __syncthreads();
    if (tid == 0) {
        uint ne = cntE < 64u ? cntE : 64u;
        uint base = cntG;   // == k - need_eq
        for (uint t2 = 0; t2 < need_eq; ++t2) {
            int best = -1, bj = -1;
            for (uint j2 = 0; j2 < ne; ++j2) {
                int v = stash[j2];
                if (v >= 0 && (best < 0 || v < best)) { best = v; bj = j2; }
            }
            if (bj >= 0) { stash[bj] = -1; emit((int)(base + t2), best); }
            else emit((int)(base + t2), 0);   // pathological fallback, never expected
        }
    }
}

// ---------------- per-batch descending sort (score, then anchor-idx asc) ----------------
__global__ __launch_bounds__(1024) void sort_kernel(
    const float* __restrict__ selScore, const float* __restrict__ selBox,
    const int* __restrict__ selValid, const int* __restrict__ selAnchor,
    int* __restrict__ sortedSlot, float* __restrict__ sortedBoxOff,
    ull* __restrict__ validMask)
{
    const int b = blockIdx.x, tid = threadIdx.x;
    __shared__ ull  skey[8192];
    __shared__ uint spay[8192];
    __shared__ ull  svm[NW];

    for (int i = tid; i < 8192; i += 1024) {
        ull kk2; uint pp;
        if (i < KSEL) {
            float s = selScore[b * KSEL + i];
            int v = selValid[b * KSEL + i];
            uint k32 = v ? fkey(s) : 0x007FFFFFu;   // invalid => key(-inf)
            uint a32 = 0xFFFFFFFFu - (uint)selAnchor[b * KSEL + i];
            kk2 = ((ull)k32 << 32) | a32; pp = (uint)i;
        } else { kk2 = 0ull; pp = 0xFFFFFFFFu; }
        skey[i] = kk2; spay[i] = pp;
    }
    __syncthreads();
    for (uint kk = 2; kk <= 8192; kk <<= 1) {
        for (uint j = kk >> 1; j > 0; j >>= 1) {
            for (int i = tid; i < 8192; i += 1024) {
                uint ixj = (uint)i ^ j;
                if (ixj > (uint)i) {
                    bool up = ((((uint)i) & kk) == 0);
                    ull a = skey[i], c = skey[ixj];
                    bool sw = up ? (a < c) : (a > c);   // flipped comparators -> descending
                    if (sw) {
                        skey[i] = c; skey[ixj] = a;
                        uint tp = spay[i]; spay[i] = spay[ixj]; spay[ixj] = tp;
                    }
                }
            }
            __syncthreads();
        }
    }
    for (int i = tid; i < NW; i += 1024) svm[i] = 0ull;
    __syncthreads();
    for (int i = tid; i < KSEL; i += 1024) {
        uint slot = spay[i];
        sortedSlot[b * KSEL + i] = (int)slot;
        int v = selValid[b * KSEL + slot];
        if (v) atomicOr(&svm[i >> 6], 1ull << (i & 63));
        int lvl = (int)slot / 1000;
        float off = 1217.0f * (float)lvl;
        float4 bx = *(const float4*)&selBox[((size_t)b * KSEL + slot) * 4];
        bx.x += off; bx.y += off; bx.z += off; bx.w += off;
        *(float4*)&sortedBoxOff[((size_t)b * KSEL + i) * 4] = bx;
    }
    __syncthreads();
    for (int i = tid; i < NW; i += 1024) validMask[b * NW + i] = svm[i];
}

// ---------------- NMS pairwise suppression bitmask ----------------
__global__ __launch_bounds__(64) void nms_mask(const float* __restrict__ sortedBoxOff,
                                               ull* __restrict__ mat)
{
    const int jb = blockIdx.x, ib = blockIdx.y, b = blockIdx.z;
    const int tid = threadIdx.x;
    __shared__ float4 bj[64];
    __shared__ float  aj[64];
    const int j0 = jb * 64;
    const int jn = (KSEL - j0) < 64 ? (KSEL - j0) : 64;
    if (tid < jn) {
        float4 v = *(const float4*)&sortedBoxOff[((size_t)b * KSEL + j0 + tid) * 4];
        bj[tid] = v; aj[tid] = (v.z - v.x) * (v.w - v.y);
    }
    __syncthreads();
    const int i = ib * 64 + tid;
    if (i >= KSEL) return;
    float4 bi = *(const float4*)&sortedBoxOff[((size_t)b * KSEL + i) * 4];
    float ai = (bi.z - bi.x) * (bi.w - bi.y);
    ull m = 0ull;
    for (int jj = 0; jj < jn; ++jj) {
        int j = j0 + jj;
        if (j <= i) continue;
        float4 bb = bj[jj];
        float ltx = fmaxf(bi.x, bb.x), lty = fmaxf(bi.y, bb.y);
        float rbx = fminf(bi.z, bb.z), rby = fminf(bi.w, bb.w);
        float wx = fmaxf(rbx - ltx, 0.f), wy = fmaxf(rby - lty, 0.f);
        float inter = wx * wy;
        float iou = inter / (ai + aj[jj] - inter + 1e-9f);
        if (iou > 0.7f) m |= (1ull << jj);
    }
    mat[((size_t)b * KSEL + i) * NW + jb] = m;
}

// ---------------- greedy scan (1 wave per batch, register-resident bitset) ----------------
__global__ __launch_bounds__(64) void nms_scan(const ull* __restrict__ mat,
                                               const ull* __restrict__ validMask,
                                               int* __restrict__ keptPos,
                                               int* __restrict__ nkOut)
{
    const int b = blockIdx.x, lane = threadIdx.x;
    ull v0 = validMask[b * NW + lane];
    ull v1 = (lane < NW - 64) ? validMask[b * NW + 64 + lane] : 0ull;
    ull s0 = 0ull, s1 = 0ull;
    int nk = 0;
    const ull* mb = mat + (size_t)b * KSEL * NW;
    const int NG = (KSEL + 7) / 8;
    for (int g = 0; g < NG; ++g) {
        ull rA[8], rB[8];
#pragma unroll
        for (int d = 0; d < 8; ++d) {
            int i = g * 8 + d;
            if (i < KSEL) {
                rA[d] = mb[(size_t)i * NW + lane];
                rB[d] = (lane < NW - 64) ? mb[(size_t)i * NW + 64 + lane] : 0ull;
            } else { rA[d] = 0ull; rB[d] = 0ull; }
        }
#pragma unroll
        for (int d = 0; d < 8; ++d) {
            int i = g * 8 + d;
            if (i >= KSEL) break;
            int wi = i >> 6;
            ull a0 = v0 & ~s0, a1 = v1 & ~s1;
            ull aw = (wi < 64) ? __shfl(a0, wi, 64) : __shfl(a1, wi - 64, 64);
            if ((aw >> (i & 63)) & 1ull) {
                s0 |= rA[d]; s1 |= rB[d];
                if (lane == 0) keptPos[b * POST_NMS + nk] = i;
                ++nk;
                if (nk == POST_NMS) { if (lane == 0) nkOut[b] = nk; return; }
            }
        }
    }
    if (lane == 0) nkOut[b] = nk;
}

// ---------------- final output ----------------
__global__ __launch_bounds__(256) void out_kernel(
    const int* __restrict__ keptPos, const int* __restrict__ nkOut,
    const int* __restrict__ sortedSlot,
    const float* __restrict__ selBox, const float* __restrict__ selScore,
    float* __restrict__ out)
{
    int t = blockIdx.x * 256 + threadIdx.x;
    if (t >= BATCH * POST_NMS) return;
    int b = t / POST_NMS, row = t - b * POST_NMS;
    float4 bx = make_float4(0.f, 0.f, 0.f, 0.f);
    float sc = -1e9f;
    if (row < nkOut[b]) {
        int i = keptPos[b * POST_NMS + row];
        int slot = sortedSlot[b * KSEL + i];
        bx = *(const float4*)&selBox[((size_t)b * KSEL + slot) * 4];
        sc = selScore[b * KSEL + slot];
    }
    *(float4*)&out[(size_t)t * 4] = bx;
    out[BATCH * POST_NMS * 4 + t] = sc;
}

// ---------------- host launch ----------------
extern "C" void kernel_launch(void* const* d_in, const int* in_sizes, int n_in,
                              void* d_out, int out_size, void* d_ws, size_t ws_size,
                              hipStream_t stream)
{
    (void)in_sizes; (void)n_in; (void)out_size; (void)ws_size;
    const float* feat[5] = {(const float*)d_in[0], (const float*)d_in[1],
                            (const float*)d_in[2], (const float*)d_in[3],
                            (const float*)d_in[4]};
    const float* conv_w = (const float*)d_in[5];
    const float* conv_b = (const float*)d_in[6];
    const float* cls_w  = (const float*)d_in[7];
    const float* cls_b  = (const float*)d_in[8];
    const float* box_w  = (const float*)d_in[9];
    const float* box_b  = (const float*)d_in[10];
    float* out = (float*)d_out;

    char* ws = (char*)d_ws;
    size_t off = 0;
    auto carve = [&](size_t bytes) -> void* {
        void* p = (void*)(ws + off);
        off += (bytes + 255) & ~(size_t)255;
        return p;
    };
    float* wT          = (float*)carve((size_t)2304 * 256 * 4);
    float* scoresA     = (float*)carve((size_t)BATCH * ATOTAL * 4);
    float* boxesA      = (float*)carve((size_t)BATCH * ATOTAL * 16);
    float* selScore    = (float*)carve((size_t)BATCH * KSEL * 4);
    float* selBox      = (float*)carve((size_t)BATCH * KSEL * 16);
    int*   selValid    = (int*)  carve((size_t)BATCH * KSEL * 4);
    int*   selAnchor   = (int*)  carve((size_t)BATCH * KSEL * 4);
    int*   sortedSlot  = (int*)  carve((size_t)BATCH * KSEL * 4);
    float* sortedBoxOff= (float*)carve((size_t)BATCH * KSEL * 16);
    ull*   validMask   = (ull*)  carve((size_t)BATCH * NW * 8);
    ull*   mat         = (ull*)  carve((size_t)BATCH * KSEL * NW * 8);
    int*   keptPos     = (int*)  carve((size_t)BATCH * POST_NMS * 4);
    int*   nkOut       = (int*)  carve(64);

    wt_kernel<<<2304, 256, 0, stream>>>(conv_w, wT);

    {
        constexpr int t0 = ((cH[0]+3)/4) * ((cW[0]+15)/16);
        conv_fused<0><<<dim3(t0, BATCH), 256, 0, stream>>>(feat[0], wT, conv_b, cls_w, cls_b, box_w, box_b, scoresA, boxesA);
    }
    {
        constexpr int t1 = ((cH[1]+3)/4) * ((cW[1]+15)/16);
        conv_fused<1><<<dim3(t1, BATCH), 256, 0, stream>>>(feat[1], wT, conv_b, cls_w, cls_b, box_w, box_b, scoresA, boxesA);
    }
    {
        constexpr int t2 = ((cH[2]+3)/4) * ((cW[2]+15)/16);
        conv_fused<2><<<dim3(t2, BATCH), 256, 0, stream>>>(feat[2], wT, conv_b, cls_w, cls_b, box_w, box_b, scoresA, boxesA);
    }
    {
        constexpr int t3 = ((cH[3]+3)/4) * ((cW[3]+15)/16);
        conv_fused<3><<<dim3(t3, BATCH), 256, 0, stream>>>(feat[3], wT, conv_b, cls_w, cls_b, box_w, box_b, scoresA, boxesA);
    }
    {
        constexpr int t4 = ((cH[4]+3)/4) * ((cW[4]+15)/16);
        conv_fused<4><<<dim3(t4, BATCH), 256, 0, stream>>>(feat[4], wT, conv_b, cls_w, cls_b, box_w, box_b, scoresA, boxesA);
    }

    topk_kernel<<<dim3(5, BATCH), 256, 0, stream>>>(scoresA, boxesA, selScore, selBox, selValid, selAnchor);
    sort_kernel<<<dim3(BATCH), 1024, 0, stream>>>(selScore, selBox, selValid, selAnchor, sortedSlot, sortedBoxOff, validMask);
    nms_mask<<<dim3(NW, NW, BATCH), 64, 0, stream>>>(sortedBoxOff, mat);
    nms_scan<<<dim3(BATCH), 64, 0, stream>>>(mat, validMask, keptPos, nkOut);
    out_kernel<<<dim3((BATCH * POST_NMS + 255) / 256), 256, 0, stream>>>(keptPos, nkOut, sortedSlot, selBox, selScore, out);
}